// Round 15
// baseline (6613.077 us; speedup 1.0000x reference)
//
#include <hip/hip_runtime.h>

// ---------- types / helpers ----------
typedef short short8 __attribute__((ext_vector_type(8)));
typedef __bf16 bf16x8 __attribute__((ext_vector_type(8)));
typedef float f32x4 __attribute__((ext_vector_type(4)));
typedef float f32x4v __attribute__((ext_vector_type(4)));
typedef unsigned short u16x4 __attribute__((ext_vector_type(4)));
typedef unsigned int u32x4 __attribute__((ext_vector_type(4)));
typedef unsigned long long u64;

__device__ __forceinline__ unsigned short f2b(float f) {
  unsigned x = __builtin_bit_cast(unsigned, f);
  x = x + 0x7fffu + ((x >> 16) & 1u);   // RNE (finite inputs)
  return (unsigned short)(x >> 16);
}
__device__ __forceinline__ float b2f(unsigned short u) {
  unsigned x = ((unsigned)u) << 16;
  return __builtin_bit_cast(float, x);
}
__device__ __forceinline__ f32x4 mfma16(short8 a, short8 b, f32x4 c) {
  return __builtin_amdgcn_mfma_f32_16x16x32_bf16(
      __builtin_bit_cast(bf16x8, a), __builtin_bit_cast(bf16x8, b), c, 0, 0, 0);
}
typedef const __attribute__((address_space(1))) void* gas_p;
typedef __attribute__((address_space(3))) void* las_p;
__device__ __forceinline__ void gload_lds16(const void* g, void* l) {
  __builtin_amdgcn_global_load_lds((gas_p)g, (las_p)l, 16, 0, 0);
}

// ---------- conversion kernels ----------
__global__ __launch_bounds__(256) void k_cvt_bf16(const float* __restrict__ in,
                                                  unsigned short* __restrict__ out,
                                                  int n4) {
  int i = blockIdx.x * 256 + threadIdx.x;
  if (i >= n4) return;
  f32x4v v = *(const f32x4v*)(in + (size_t)i * 4);
  u16x4 o;
  o[0] = f2b(v[0]); o[1] = f2b(v[1]); o[2] = f2b(v[2]); o[3] = f2b(v[3]);
  *(u16x4*)(out + (size_t)i * 4) = o;
}

// hq[b][0][i] = tag0 | bf16(h0[b][i]); hq[b][1][i] = 0  (tag 0 != any odd t)
__global__ __launch_bounds__(256) void k_init_hq(const float* __restrict__ h0,
                                                 unsigned int* __restrict__ hq) {
  int idx = blockIdx.x * 256 + threadIdx.x;
  if (idx >= 8192) return;
  int b = idx >> 10, i = idx & 1023;
  hq[(size_t)b * 2048 + i] = (unsigned int)f2b(h0[idx]);
  hq[(size_t)b * 2048 + 1024 + i] = 0u;
}

// out[c][r] = bf16(in[r][c]);  R,C multiples of 32
__global__ __launch_bounds__(256) void k_transpose_bf16(const float* __restrict__ in,
                                                        unsigned short* __restrict__ out,
                                                        int R, int C) {
  __shared__ unsigned short tile[32][33];
  int c0 = blockIdx.x * 32, r0 = blockIdx.y * 32;
  int tx = threadIdx.x & 31, ty = threadIdx.x >> 5;
#pragma unroll
  for (int i = 0; i < 4; i++) {
    int r = ty + i * 8;
    tile[r][tx] = f2b(in[(size_t)(r0 + r) * C + c0 + tx]);
  }
  __syncthreads();
#pragma unroll
  for (int i = 0; i < 4; i++) {
    int rr = ty + i * 8;
    out[(size_t)(c0 + rr) * R + r0 + tx] = tile[tx][rr];
  }
}

// ---------- GEMM1: drive = silu(u)*silu(v)+w ----------
__global__ __launch_bounds__(256) void k_gemm_drive(const unsigned short* __restrict__ xb,
                                                    const unsigned short* __restrict__ WinT,
                                                    const float* __restrict__ b_in,
                                                    unsigned short* __restrict__ drive) {
  __shared__ unsigned short At[128 * 32];
  __shared__ unsigned short Bt[3][64 * 32];
  const int tid = threadIdx.x;
  const int w = tid >> 6, l = tid & 63;
  const int wm = w >> 1, wn = w & 1;
  const int lr = l & 15, lk = (l >> 4) * 8;
  const int m0 = blockIdx.x * 128;
  const int j0 = blockIdx.y * 64;
  f32x4 acc[3][4][2];
#pragma unroll
  for (int s = 0; s < 3; s++)
#pragma unroll
    for (int mi = 0; mi < 4; mi++)
#pragma unroll
      for (int ni = 0; ni < 2; ni++)
#pragma unroll
        for (int e = 0; e < 4; e++) acc[s][mi][ni][e] = 0.f;

  const int sr = tid >> 2;
  const int skb = (tid & 3) * 8;
  for (int kt = 0; kt < 32; kt++) {
    const int k0 = kt * 32;
    gload_lds16(xb + (size_t)(m0 + sr) * 1024 + k0 + skb, &At[w * 512]);
    gload_lds16(xb + (size_t)(m0 + 64 + sr) * 1024 + k0 + skb, &At[2048 + w * 512]);
#pragma unroll
    for (int s = 0; s < 3; s++)
      gload_lds16(WinT + (size_t)(s * 1024 + j0 + sr) * 1024 + k0 + skb, &Bt[s][w * 512]);
    __syncthreads();
    short8 Af[4], Bf[3][2];
#pragma unroll
    for (int mi = 0; mi < 4; mi++)
      Af[mi] = *(const short8*)&At[(wm * 64 + mi * 16 + lr) * 32 + lk];
#pragma unroll
    for (int s = 0; s < 3; s++)
#pragma unroll
      for (int ni = 0; ni < 2; ni++)
        Bf[s][ni] = *(const short8*)&Bt[s][(wn * 32 + ni * 16 + lr) * 32 + lk];
#pragma unroll
    for (int s = 0; s < 3; s++)
#pragma unroll
      for (int mi = 0; mi < 4; mi++)
#pragma unroll
        for (int ni = 0; ni < 2; ni++)
          acc[s][mi][ni] = mfma16(Af[mi], Bf[s][ni], acc[s][mi][ni]);
    __syncthreads();
  }
#pragma unroll
  for (int ni = 0; ni < 2; ni++) {
    const int c = j0 + wn * 32 + ni * 16 + lr;
    const float bu = b_in[c], bv = b_in[1024 + c], bw = b_in[2048 + c];
#pragma unroll
    for (int mi = 0; mi < 4; mi++) {
      const int r0 = m0 + wm * 64 + mi * 16 + (l >> 4) * 4;
#pragma unroll
      for (int e = 0; e < 4; e++) {
        float u = acc[0][mi][ni][e] + bu;
        float v = acc[1][mi][ni][e] + bv;
        float wv = acc[2][mi][ni][e] + bw;
        float su = u / (1.f + __expf(-u));
        float sv = v / (1.f + __expf(-v));
        drive[(size_t)(r0 + e) * 1024 + c] = f2b(su * sv + wv);
      }
    }
  }
}

// ---------- persistent scan v15: 8-wave WG, 4-phase role-concurrent pair ----------
// 128 WGs x 512 thr (8 waves). Ring r=g>>5 serves batches {2r,2r+1}; slot
// s=g&31 owns features [32s,32s+32) of both. Exchange identical to R10/R14
// (hq[b][t&1][1024] tagged (t<<16)|bf16, sc1 relaxed agent atomics, no fence).
// Waves 0-5: MFMA (mat=w>>1, K-half kh=w&1; Breg[2][16]=128 VGPR). Waves 6-7:
// pollers (128 lanes x 4 u64/sweep) + drive->LDS prefetch. Wave0 lanes 0-31:
// finisher. Phases/pair: [MFMA_A || drive-prefetch] [finishA+pub || pollB(t)]
// [MFMA_B] [finishB+pub || pollA(t+1)]. Every poll's target was published
// >=1 phase earlier -> ~1 sweep detect; finish always overlaps a poll.
// Liveness/back-pressure: same chained argument as R10 (mates consume h(t-1)
// before our h(t+1) overwrite); all spins are on the R10-proven path.
__global__ __launch_bounds__(512, 1) void k_scan(const unsigned short* __restrict__ WgT,
                                                 const unsigned short* __restrict__ WrT,
                                                 const float* __restrict__ b_gate,
                                                 const float* __restrict__ b_rec,
                                                 const unsigned short* __restrict__ drive,
                                                 unsigned int* __restrict__ hq,
                                                 unsigned short* __restrict__ hs,
                                                 float* __restrict__ final_h) {
  const int g = blockIdx.x;           // 0..127
  const int r = g >> 5;               // ring id 0..3
  const int s = g & 31;               // slot in ring
  const int tid = threadIdx.x;        // 0..511
  const int w = tid >> 6, l = tid & 63;
  const int bA = 2 * r, bB = 2 * r + 1;

  __shared__ unsigned int tileh[2][512];     // packed h per batch (2KB each)
  __shared__ float buf[2][2][3][32];         // [batch][kh][mat][col] row-0
  __shared__ unsigned short dd[2][32];       // prefetched drive values

  // ---- MFMA setup (w<6): mat=w>>1, kh=w&1; B-frags -> 128 VGPR ----
  const int mat = w >> 1, kh = w & 1;
  const int lr = l & 15, ko = l >> 4;
  const bool av = (lr == 0);
  short8 Breg0[16], Breg1[16];
  if (w < 6) {
    const unsigned short* WT = (mat == 2) ? WrT : WgT;
    const int rowbase = ((mat == 1) ? 1024 : 0) + s * 32;
#pragma unroll
    for (int ks = 0; ks < 16; ++ks) {
      Breg0[ks] = *(const short8*)&WT[(size_t)(rowbase + lr) * 1024 +
                                      kh * 512 + ks * 32 + ko * 8];
      Breg1[ks] = *(const short8*)&WT[(size_t)(rowbase + 16 + lr) * 1024 +
                                      kh * 512 + ks * 32 + ko * 8];
    }
  }

  // ---- poller setup (w>=6): lane P owns u64 words 4P..4P+3 ----
  const bool ispl = (w >= 6);
  const int P = ((w - 6) << 6) | l;   // 0..127 (valid when ispl)

  // ---- finisher setup (w==0, l<32) ----
  const bool isfin = (w == 0) && (l < 32);
  const int fcol = s * 32 + l;        // valid for l<32
  float bgv = 0.f, bgt = 0.f, brc = 0.f;
  if (isfin) { bgv = b_gate[fcol]; bgt = b_gate[1024 + fcol]; brc = b_rec[fcol]; }

  // ---- poll helper (lambda): sweep 4 u64, validate tags, pack to LDS ----
  auto poll4 = [&](const u64* base, unsigned tg, unsigned int* dst) {
    const u64* p = base + 4 * P;
    u64 v[4];
    unsigned pend = 0xFu;
    do {
      unsigned np = 0;
#pragma unroll
      for (int j = 0; j < 4; ++j)
        if ((pend >> j) & 1)
          v[j] = __hip_atomic_load(p + j, __ATOMIC_RELAXED,
                                   __HIP_MEMORY_SCOPE_AGENT);
#pragma unroll
      for (int j = 0; j < 4; ++j)
        if ((pend >> j) & 1) {
          if ((((unsigned)v[j] >> 16) != tg) |
              (((unsigned)(v[j] >> 32) >> 16) != tg))
            np |= 1u << j;
        }
      pend = np;
    } while (pend);
    u32x4 pk;
#pragma unroll
    for (int j = 0; j < 4; ++j)
      pk[j] = __builtin_amdgcn_perm((unsigned)(v[j] >> 32), (unsigned)v[j],
                                    0x05040100u);
    *(u32x4*)&dst[4 * P] = pk;
  };

  // ---- MFMA helper: one batch step, full 32 features x this wave's K-half ----
  auto mfma_phase = [&](int X) {
    f32x4 a0, a1, c0, c1;
#pragma unroll
    for (int e = 0; e < 4; ++e) { a0[e] = 0.f; a1[e] = 0.f; c0[e] = 0.f; c1[e] = 0.f; }
    const char* base = (const char*)&tileh[X][0] + kh * 1024 + ko * 16;
#pragma unroll
    for (int ks = 0; ks < 16; ++ks) {
      short8 Af;
#pragma unroll
      for (int e = 0; e < 8; ++e) Af[e] = 0;
      if (av) Af = *(const short8*)(base + ks * 64);
      if (ks & 1) { a1 = mfma16(Af, Breg0[ks], a1); c1 = mfma16(Af, Breg1[ks], c1); }
      else        { a0 = mfma16(Af, Breg0[ks], a0); c0 = mfma16(Af, Breg1[ks], c0); }
    }
    if (l < 16) {
      buf[X][kh][mat][l] = a0[0] + a1[0];
      buf[X][kh][mat][16 + l] = c0[0] + c1[0];
    }
  };

  // ---- finisher helper ----
  auto finish = [&](int X, int b, int t) {
    const float gv = buf[X][0][0][l] + buf[X][1][0][l] + bgv;
    const float gt = buf[X][0][1][l] + buf[X][1][1][l] + bgt;
    const float rc = buf[X][0][2][l] + buf[X][1][2][l] + brc;
    const float sgv = 1.f / (1.f + __expf(-gv));
    const float sgt = 1.f / (1.f + __expf(-gt));
    const float gate = sgv * gt * sgt;  // sigmoid(gv) * silu(gt)
    const float nh = gate * rc + (1.f - gate) * b2f(dd[X][l]);
    const unsigned short nhb = f2b(nh);
    __hip_atomic_store(hq + (size_t)(b * 2 + ((t + 1) & 1)) * 1024 + fcol,
                       (((unsigned)(t + 1)) << 16) | (unsigned)nhb,
                       __ATOMIC_RELAXED, __HIP_MEMORY_SCOPE_AGENT);
    hs[(size_t)(b * 2048 + t) * 1024 + fcol] = nhb;
    if (t == 2047) final_h[b * 1024 + fcol] = nh;
  };

  // ---- prologue: fetch h_A(0), h_B(0) (tag 0, seeded) ----
  if (ispl) {
    poll4((const u64*)(hq + (size_t)(bA * 2) * 1024), 0u, &tileh[0][0]);
    poll4((const u64*)(hq + (size_t)(bB * 2) * 1024), 0u, &tileh[1][0]);
  }
  __syncthreads();

  for (int t = 0; t < 2048; ++t) {
    // ph1: MFMA_A(h_A(t)) || pollers prefetch drive values
    if (w < 6) mfma_phase(0);
    else if (l < 32) {
      if (w == 6) dd[0][l] = drive[((size_t)bA * 2048 + t) * 1024 + s * 32 + l];
      else        dd[1][l] = drive[((size_t)bB * 2048 + t) * 1024 + s * 32 + l];
    }
    __syncthreads();

    // ph2: finishA -> publish h_A(t+1)  ||  pollB(t)  (t=0 done in prologue)
    if (isfin) finish(0, bA, t);
    if (ispl && t > 0)
      poll4((const u64*)(hq + (size_t)(bB * 2 + (t & 1)) * 1024), (unsigned)t,
            &tileh[1][0]);
    __syncthreads();

    // ph3: MFMA_B(h_B(t))
    if (w < 6) mfma_phase(1);
    __syncthreads();

    // ph4: finishB -> publish h_B(t+1)  ||  pollA(t+1)
    if (isfin) finish(1, bB, t);
    if (ispl && t < 2047)
      poll4((const u64*)(hq + (size_t)(bA * 2 + ((t + 1) & 1)) * 1024),
            (unsigned)(t + 1), &tileh[0][0]);
    __syncthreads();
  }
}

// ---------- GEMM3: out = hs @ W_out + b_out ----------
__global__ __launch_bounds__(256) void k_gemm_out(const unsigned short* __restrict__ hs,
                                                  const unsigned short* __restrict__ WoT,
                                                  const float* __restrict__ b_out,
                                                  float* __restrict__ out) {
  __shared__ unsigned short At[128 * 32];
  __shared__ unsigned short Bt[128 * 32];
  const int tid = threadIdx.x;
  const int w = tid >> 6, l = tid & 63;
  const int wm = w >> 1, wn = w & 1;
  const int lr = l & 15, lk = (l >> 4) * 8;
  const int m0 = blockIdx.x * 128;
  const int n0 = blockIdx.y * 128;
  f32x4 acc[4][4];
#pragma unroll
  for (int mi = 0; mi < 4; mi++)
#pragma unroll
    for (int ni = 0; ni < 4; ni++)
#pragma unroll
      for (int e = 0; e < 4; e++) acc[mi][ni][e] = 0.f;

  const int sr = tid >> 2;
  const int skb = (tid & 3) * 8;
  for (int kt = 0; kt < 32; kt++) {
    const int k0 = kt * 32;
    gload_lds16(hs + (size_t)(m0 + sr) * 1024 + k0 + skb, &At[w * 512]);
    gload_lds16(hs + (size_t)(m0 + 64 + sr) * 1024 + k0 + skb, &At[2048 + w * 512]);
    gload_lds16(WoT + (size_t)(n0 + sr) * 1024 + k0 + skb, &Bt[w * 512]);
    gload_lds16(WoT + (size_t)(n0 + 64 + sr) * 1024 + k0 + skb, &Bt[2048 + w * 512]);
    __syncthreads();
    short8 Af[4], Bf[4];
#pragma unroll
    for (int mi = 0; mi < 4; mi++)
      Af[mi] = *(const short8*)&At[(wm * 64 + mi * 16 + lr) * 32 + lk];
#pragma unroll
    for (int ni = 0; ni < 4; ni++)
      Bf[ni] = *(const short8*)&Bt[(wn * 64 + ni * 16 + lr) * 32 + lk];
#pragma unroll
    for (int mi = 0; mi < 4; mi++)
#pragma unroll
      for (int ni = 0; ni < 4; ni++)
        acc[mi][ni] = mfma16(Af[mi], Bf[ni], acc[mi][ni]);
    __syncthreads();
  }
#pragma unroll
  for (int ni = 0; ni < 4; ni++) {
    const int c = n0 + wn * 64 + ni * 16 + lr;
    const float bo = b_out[c];
#pragma unroll
    for (int mi = 0; mi < 4; mi++) {
      const int r0 = m0 + wm * 64 + mi * 16 + (l >> 4) * 4;
#pragma unroll
      for (int e = 0; e < 4; e++)
        out[(size_t)(r0 + e) * 1024 + c] = acc[mi][ni][e] + bo;
    }
  }
}

// ---------- launch ----------
extern "C" void kernel_launch(void* const* d_in, const int* in_sizes, int n_in,
                              void* d_out, int out_size, void* d_ws, size_t ws_size,
                              hipStream_t stream) {
  const float* x      = (const float*)d_in[0];
  const float* h0     = (const float*)d_in[1];
  const float* W_in   = (const float*)d_in[2];
  const float* b_in   = (const float*)d_in[3];
  const float* W_gate = (const float*)d_in[4];
  const float* b_gate = (const float*)d_in[5];
  const float* W_rec  = (const float*)d_in[6];
  const float* b_rec  = (const float*)d_in[7];
  const float* W_out  = (const float*)d_in[8];
  const float* b_out  = (const float*)d_in[9];
  float* outp = (float*)d_out;

  size_t off = 0;
  auto alloc = [&](size_t bytes) {
    void* p = (char*)d_ws + off;
    off += (bytes + 255) & ~(size_t)255;
    return p;
  };
  unsigned short* xb    = (unsigned short*)alloc((size_t)16777216 * 2);
  unsigned short* WinT  = (unsigned short*)alloc((size_t)3072 * 1024 * 2);
  unsigned short* WgT   = (unsigned short*)alloc((size_t)2048 * 1024 * 2);
  unsigned short* WrT   = (unsigned short*)alloc((size_t)1024 * 1024 * 2);
  unsigned short* WoT   = (unsigned short*)alloc((size_t)1024 * 1024 * 2);
  unsigned short* drive = (unsigned short*)alloc((size_t)16777216 * 2);
  unsigned short* hs    = (unsigned short*)alloc((size_t)16777216 * 2);
  unsigned int*   hq    = (unsigned int*)alloc((size_t)8 * 2 * 1024 * 4);  // 64KB

  // conversions / init
  k_cvt_bf16<<<16384, 256, 0, stream>>>(x, xb, 4194304);
  k_transpose_bf16<<<dim3(96, 32), 256, 0, stream>>>(W_in, WinT, 1024, 3072);
  k_transpose_bf16<<<dim3(64, 32), 256, 0, stream>>>(W_gate, WgT, 1024, 2048);
  k_transpose_bf16<<<dim3(32, 32), 256, 0, stream>>>(W_rec, WrT, 1024, 1024);
  k_transpose_bf16<<<dim3(32, 32), 256, 0, stream>>>(W_out, WoT, 1024, 1024);
  k_init_hq<<<32, 256, 0, stream>>>(h0, hq);

  // drive = silu(u)*silu(v)+w
  k_gemm_drive<<<dim3(128, 16), 256, 0, stream>>>(xb, WinT, b_in, drive);
  // sequential recurrence: 4 rings x 32 WGs, 8-wave WGs, 4-phase pair schedule
  k_scan<<<128, 512, 0, stream>>>(WgT, WrT, b_gate, b_rec, drive, hq,
                                  hs, outp + 16777216);
  // out = hs @ W_out + b_out
  k_gemm_out<<<dim3(128, 8), 256, 0, stream>>>(hs, WoT, b_out, outp);
}

// Round 16
// 4408.984 us; speedup vs baseline: 1.4999x; 1.4999x over previous
//
#include <hip/hip_runtime.h>

// ---------- types / helpers ----------
typedef short short8 __attribute__((ext_vector_type(8)));
typedef __bf16 bf16x8 __attribute__((ext_vector_type(8)));
typedef float f32x4 __attribute__((ext_vector_type(4)));
typedef float f32x4v __attribute__((ext_vector_type(4)));
typedef unsigned short u16x4 __attribute__((ext_vector_type(4)));
typedef unsigned int uint2v __attribute__((ext_vector_type(2)));
typedef unsigned long long u64;

__device__ __forceinline__ unsigned short f2b(float f) {
  unsigned x = __builtin_bit_cast(unsigned, f);
  x = x + 0x7fffu + ((x >> 16) & 1u);   // RNE (finite inputs)
  return (unsigned short)(x >> 16);
}
__device__ __forceinline__ float b2f(unsigned short u) {
  unsigned x = ((unsigned)u) << 16;
  return __builtin_bit_cast(float, x);
}
__device__ __forceinline__ f32x4 mfma16(short8 a, short8 b, f32x4 c) {
  return __builtin_amdgcn_mfma_f32_16x16x32_bf16(
      __builtin_bit_cast(bf16x8, a), __builtin_bit_cast(bf16x8, b), c, 0, 0, 0);
}
typedef const __attribute__((address_space(1))) void* gas_p;
typedef __attribute__((address_space(3))) void* las_p;
__device__ __forceinline__ void gload_lds16(const void* g, void* l) {
  __builtin_amdgcn_global_load_lds((gas_p)g, (las_p)l, 16, 0, 0);
}

// ---------- conversion kernels ----------
__global__ __launch_bounds__(256) void k_cvt_bf16(const float* __restrict__ in,
                                                  unsigned short* __restrict__ out,
                                                  int n4) {
  int i = blockIdx.x * 256 + threadIdx.x;
  if (i >= n4) return;
  f32x4v v = *(const f32x4v*)(in + (size_t)i * 4);
  u16x4 o;
  o[0] = f2b(v[0]); o[1] = f2b(v[1]); o[2] = f2b(v[2]); o[3] = f2b(v[3]);
  *(u16x4*)(out + (size_t)i * 4) = o;
}

// hq[b][0][i] = tag0 | bf16(h0[b][i]); hq[b][1][i] = 0  (tag 0 != any odd t)
__global__ __launch_bounds__(256) void k_init_hq(const float* __restrict__ h0,
                                                 unsigned int* __restrict__ hq) {
  int idx = blockIdx.x * 256 + threadIdx.x;
  if (idx >= 8192) return;
  int b = idx >> 10, i = idx & 1023;
  hq[(size_t)b * 2048 + i] = (unsigned int)f2b(h0[idx]);
  hq[(size_t)b * 2048 + 1024 + i] = 0u;
}

// out[c][r] = bf16(in[r][c]);  R,C multiples of 32
__global__ __launch_bounds__(256) void k_transpose_bf16(const float* __restrict__ in,
                                                        unsigned short* __restrict__ out,
                                                        int R, int C) {
  __shared__ unsigned short tile[32][33];
  int c0 = blockIdx.x * 32, r0 = blockIdx.y * 32;
  int tx = threadIdx.x & 31, ty = threadIdx.x >> 5;
#pragma unroll
  for (int i = 0; i < 4; i++) {
    int r = ty + i * 8;
    tile[r][tx] = f2b(in[(size_t)(r0 + r) * C + c0 + tx]);
  }
  __syncthreads();
#pragma unroll
  for (int i = 0; i < 4; i++) {
    int rr = ty + i * 8;
    out[(size_t)(c0 + rr) * R + r0 + tx] = tile[tx][rr];
  }
}

// ---------- GEMM1: drive = silu(u)*silu(v)+w ----------
__global__ __launch_bounds__(256) void k_gemm_drive(const unsigned short* __restrict__ xb,
                                                    const unsigned short* __restrict__ WinT,
                                                    const float* __restrict__ b_in,
                                                    unsigned short* __restrict__ drive) {
  __shared__ unsigned short At[128 * 32];
  __shared__ unsigned short Bt[3][64 * 32];
  const int tid = threadIdx.x;
  const int w = tid >> 6, l = tid & 63;
  const int wm = w >> 1, wn = w & 1;
  const int lr = l & 15, lk = (l >> 4) * 8;
  const int m0 = blockIdx.x * 128;
  const int j0 = blockIdx.y * 64;
  f32x4 acc[3][4][2];
#pragma unroll
  for (int s = 0; s < 3; s++)
#pragma unroll
    for (int mi = 0; mi < 4; mi++)
#pragma unroll
      for (int ni = 0; ni < 2; ni++)
#pragma unroll
        for (int e = 0; e < 4; e++) acc[s][mi][ni][e] = 0.f;

  const int sr = tid >> 2;
  const int skb = (tid & 3) * 8;
  for (int kt = 0; kt < 32; kt++) {
    const int k0 = kt * 32;
    gload_lds16(xb + (size_t)(m0 + sr) * 1024 + k0 + skb, &At[w * 512]);
    gload_lds16(xb + (size_t)(m0 + 64 + sr) * 1024 + k0 + skb, &At[2048 + w * 512]);
#pragma unroll
    for (int s = 0; s < 3; s++)
      gload_lds16(WinT + (size_t)(s * 1024 + j0 + sr) * 1024 + k0 + skb, &Bt[s][w * 512]);
    __syncthreads();
    short8 Af[4], Bf[3][2];
#pragma unroll
    for (int mi = 0; mi < 4; mi++)
      Af[mi] = *(const short8*)&At[(wm * 64 + mi * 16 + lr) * 32 + lk];
#pragma unroll
    for (int s = 0; s < 3; s++)
#pragma unroll
      for (int ni = 0; ni < 2; ni++)
        Bf[s][ni] = *(const short8*)&Bt[s][(wn * 32 + ni * 16 + lr) * 32 + lk];
#pragma unroll
    for (int s = 0; s < 3; s++)
#pragma unroll
      for (int mi = 0; mi < 4; mi++)
#pragma unroll
        for (int ni = 0; ni < 2; ni++)
          acc[s][mi][ni] = mfma16(Af[mi], Bf[s][ni], acc[s][mi][ni]);
    __syncthreads();
  }
#pragma unroll
  for (int ni = 0; ni < 2; ni++) {
    const int c = j0 + wn * 32 + ni * 16 + lr;
    const float bu = b_in[c], bv = b_in[1024 + c], bw = b_in[2048 + c];
#pragma unroll
    for (int mi = 0; mi < 4; mi++) {
      const int r0 = m0 + wm * 64 + mi * 16 + (l >> 4) * 4;
#pragma unroll
      for (int e = 0; e < 4; e++) {
        float u = acc[0][mi][ni][e] + bu;
        float v = acc[1][mi][ni][e] + bv;
        float wv = acc[2][mi][ni][e] + bw;
        float su = u / (1.f + __expf(-u));
        float sv = v / (1.f + __expf(-v));
        drive[(size_t)(r0 + e) * 1024 + c] = f2b(su * sv + wv);
      }
    }
  }
}

// ---------- persistent scan v16: self-served polls, ONE barrier/step ----------
// 256 WGs x 832 thr (13 waves). Ring=batch b=g>>5, slot s=g&31 (R10 layout).
// Exchange protocol identical to R10 (hq[b][t&1][1024] tagged (t<<16)|bf16,
// sc1 relaxed agent atomics). NEW: no dedicated poller waves - each MFMA wave
// (mat=w>>2, kq=w&3) polls ITS OWN kq-quarter of h (64 lanes x 2 u64 = 256
// features) into a private LDS strip, then MFMAs immediately: producer=
// consumer=same wave -> no pre-MFMA barrier. buf is double-buffered ->
// ONE __syncthreads per step (MFMA->finisher handoff). Wave 12 = finisher:
// K-quarter reduce, gate math, publish tag t+1; its publish overlaps the
// MFMA waves' next poll. Hazards: buf[p] rewrite at t+2 gated through our
// own finisher's publish chain (verified); 3-mat poll redundancy accepted
// (R5/R6: exchange traffic volume is not a cost driver).
__global__ __launch_bounds__(832, 1) void k_scan(const unsigned short* __restrict__ WgT,
                                                 const unsigned short* __restrict__ WrT,
                                                 const float* __restrict__ b_gate,
                                                 const float* __restrict__ b_rec,
                                                 const unsigned short* __restrict__ drive,
                                                 unsigned int* __restrict__ hq,
                                                 unsigned short* __restrict__ hs,
                                                 float* __restrict__ final_h) {
  const int g = blockIdx.x;           // 0..255
  const int b = g >> 5;               // batch / ring id
  const int s = g & 31;               // slot in ring
  const int tid = threadIdx.x;        // 0..831
  const int w = tid >> 6, l = tid & 63;

  __shared__ unsigned int tile[12][128];   // per-wave packed kq-slice (512B)
  __shared__ float buf[2][4][3][32];       // double-buffered partials

  // ---- MFMA-wave setup (w<12): B-frags -> registers (2 tiles x 8 = 64 VGPR) ----
  const int mat = w >> 2, kq = w & 3;
  const int lr = l & 15, ko = l >> 4;
  const bool av = (lr == 0);               // A row-0 carrier lanes
  short8 Breg[2][8];
  if (w < 12) {
    const unsigned short* WT = (mat == 2) ? WrT : WgT;
    const int rowbase = ((mat == 1) ? 1024 : 0) + s * 32;
#pragma unroll
    for (int t2 = 0; t2 < 2; ++t2)
#pragma unroll
      for (int ks = 0; ks < 8; ++ks)
        Breg[t2][ks] = *(const short8*)&WT[(size_t)(rowbase + t2 * 16 + lr) * 1024 +
                                           kq * 256 + ks * 32 + ko * 8];
  }

  // ---- finisher setup (wave 12, lanes 0-31) ----
  const bool isfin = (w == 12) && (l < 32);
  const int fcol = s * 32 + l;             // valid when isfin
  float bgv = 0.f, bgt = 0.f, brc = 0.f;
  unsigned short dpf = 0;
  if (isfin) {
    bgv = b_gate[fcol]; bgt = b_gate[1024 + fcol]; brc = b_rec[fcol];
    dpf = drive[(size_t)(b * 2048 + 0) * 1024 + fcol];
  }

  for (int t = 0; t < 2048; ++t) {
    const int p = t & 1;

    if (w < 12) {
      // ---- poll OWN kq-slice of h_t (tags == t), 2 u64 per lane ----
      const unsigned tg = (unsigned)t;
      const u64* hb = (const u64*)(hq + (size_t)(b * 2 + p) * 1024) + kq * 128 + 2 * l;
      u64 v0 = 0, v1 = 0;
      unsigned pend = 3u;
      do {
        if (pend & 1u)
          v0 = __hip_atomic_load(hb, __ATOMIC_RELAXED, __HIP_MEMORY_SCOPE_AGENT);
        if (pend & 2u)
          v1 = __hip_atomic_load(hb + 1, __ATOMIC_RELAXED, __HIP_MEMORY_SCOPE_AGENT);
        unsigned np = 0;
        if ((((unsigned)v0 >> 16) != tg) | (((unsigned)(v0 >> 32) >> 16) != tg))
          np |= 1u;
        if ((((unsigned)v1 >> 16) != tg) | (((unsigned)(v1 >> 32) >> 16) != tg))
          np |= 2u;
        pend = np;
      } while (pend);
      uint2v pk;
      pk[0] = __builtin_amdgcn_perm((unsigned)(v0 >> 32), (unsigned)v0, 0x05040100u);
      pk[1] = __builtin_amdgcn_perm((unsigned)(v1 >> 32), (unsigned)v1, 0x05040100u);
      *(uint2v*)&tile[w][2 * l] = pk;   // own strip; read back by same wave

      // ---- MFMA immediately (no barrier: intra-wave LDS dependency only) ----
      f32x4 a0, a1;
#pragma unroll
      for (int e = 0; e < 4; ++e) { a0[e] = 0.f; a1[e] = 0.f; }
      const char* base = (const char*)&tile[w][0] + ko * 16;
#pragma unroll
      for (int ks = 0; ks < 8; ++ks) {
        short8 Af;
#pragma unroll
        for (int e = 0; e < 8; ++e) Af[e] = 0;
        if (av) Af = *(const short8*)(base + ks * 64);
        a0 = mfma16(Af, Breg[0][ks], a0);
        a1 = mfma16(Af, Breg[1][ks], a1);
      }
      if (l < 16) {   // D row 0 lives in lanes 0-15, reg 0
        buf[p][kq][mat][l] = a0[0];
        buf[p][kq][mat][16 + l] = a1[0];
      }
    }
    __syncthreads();   // the ONLY barrier: buf[p] ready for the finisher

    // ---- finisher (wave 12): K-quarter reduce + gate + tagged publish ----
    // Overlaps the MFMA waves' next-step polls (they've already advanced).
    if (isfin) {
      const float gv = ((buf[p][0][0][l] + buf[p][1][0][l]) +
                        (buf[p][2][0][l] + buf[p][3][0][l])) + bgv;
      const float gt = ((buf[p][0][1][l] + buf[p][1][1][l]) +
                        (buf[p][2][1][l] + buf[p][3][1][l])) + bgt;
      const float rc = ((buf[p][0][2][l] + buf[p][1][2][l]) +
                        (buf[p][2][2][l] + buf[p][3][2][l])) + brc;
      const float sgv = 1.f / (1.f + __expf(-gv));
      const float sgt = 1.f / (1.f + __expf(-gt));
      const float gate = sgv * gt * sgt;  // sigmoid(gv) * silu(gt)
      const float nh = gate * rc + (1.f - gate) * b2f(dpf);
      const unsigned short nhb = f2b(nh);
      __hip_atomic_store(hq + (size_t)(b * 2 + (p ^ 1)) * 1024 + fcol,
                         (((unsigned)(t + 1)) << 16) | (unsigned)nhb,
                         __ATOMIC_RELAXED, __HIP_MEMORY_SCOPE_AGENT);
      hs[(size_t)(b * 2048 + t) * 1024 + fcol] = nhb;
      if (t == 2047) final_h[b * 1024 + fcol] = nh;
      else dpf = drive[(size_t)(b * 2048 + t + 1) * 1024 + fcol];  // prefetch
    }
  }
}

// ---------- GEMM3: out = hs @ W_out + b_out ----------
__global__ __launch_bounds__(256) void k_gemm_out(const unsigned short* __restrict__ hs,
                                                  const unsigned short* __restrict__ WoT,
                                                  const float* __restrict__ b_out,
                                                  float* __restrict__ out) {
  __shared__ unsigned short At[128 * 32];
  __shared__ unsigned short Bt[128 * 32];
  const int tid = threadIdx.x;
  const int w = tid >> 6, l = tid & 63;
  const int wm = w >> 1, wn = w & 1;
  const int lr = l & 15, lk = (l >> 4) * 8;
  const int m0 = blockIdx.x * 128;
  const int n0 = blockIdx.y * 128;
  f32x4 acc[4][4];
#pragma unroll
  for (int mi = 0; mi < 4; mi++)
#pragma unroll
    for (int ni = 0; ni < 4; ni++)
#pragma unroll
      for (int e = 0; e < 4; e++) acc[mi][ni][e] = 0.f;

  const int sr = tid >> 2;
  const int skb = (tid & 3) * 8;
  for (int kt = 0; kt < 32; kt++) {
    const int k0 = kt * 32;
    gload_lds16(hs + (size_t)(m0 + sr) * 1024 + k0 + skb, &At[w * 512]);
    gload_lds16(hs + (size_t)(m0 + 64 + sr) * 1024 + k0 + skb, &At[2048 + w * 512]);
    gload_lds16(WoT + (size_t)(n0 + sr) * 1024 + k0 + skb, &Bt[w * 512]);
    gload_lds16(WoT + (size_t)(n0 + 64 + sr) * 1024 + k0 + skb, &Bt[2048 + w * 512]);
    __syncthreads();
    short8 Af[4], Bf[4];
#pragma unroll
    for (int mi = 0; mi < 4; mi++)
      Af[mi] = *(const short8*)&At[(wm * 64 + mi * 16 + lr) * 32 + lk];
#pragma unroll
    for (int ni = 0; ni < 4; ni++)
      Bf[ni] = *(const short8*)&Bt[(wn * 64 + ni * 16 + lr) * 32 + lk];
#pragma unroll
    for (int mi = 0; mi < 4; mi++)
#pragma unroll
      for (int ni = 0; ni < 4; ni++)
        acc[mi][ni] = mfma16(Af[mi], Bf[ni], acc[mi][ni]);
    __syncthreads();
  }
#pragma unroll
  for (int ni = 0; ni < 4; ni++) {
    const int c = n0 + wn * 64 + ni * 16 + lr;
    const float bo = b_out[c];
#pragma unroll
    for (int mi = 0; mi < 4; mi++) {
      const int r0 = m0 + wm * 64 + mi * 16 + (l >> 4) * 4;
#pragma unroll
      for (int e = 0; e < 4; e++)
        out[(size_t)(r0 + e) * 1024 + c] = acc[mi][ni][e] + bo;
    }
  }
}

// ---------- launch ----------
extern "C" void kernel_launch(void* const* d_in, const int* in_sizes, int n_in,
                              void* d_out, int out_size, void* d_ws, size_t ws_size,
                              hipStream_t stream) {
  const float* x      = (const float*)d_in[0];
  const float* h0     = (const float*)d_in[1];
  const float* W_in   = (const float*)d_in[2];
  const float* b_in   = (const float*)d_in[3];
  const float* W_gate = (const float*)d_in[4];
  const float* b_gate = (const float*)d_in[5];
  const float* W_rec  = (const float*)d_in[6];
  const float* b_rec  = (const float*)d_in[7];
  const float* W_out  = (const float*)d_in[8];
  const float* b_out  = (const float*)d_in[9];
  float* outp = (float*)d_out;

  size_t off = 0;
  auto alloc = [&](size_t bytes) {
    void* p = (char*)d_ws + off;
    off += (bytes + 255) & ~(size_t)255;
    return p;
  };
  unsigned short* xb    = (unsigned short*)alloc((size_t)16777216 * 2);
  unsigned short* WinT  = (unsigned short*)alloc((size_t)3072 * 1024 * 2);
  unsigned short* WgT   = (unsigned short*)alloc((size_t)2048 * 1024 * 2);
  unsigned short* WrT   = (unsigned short*)alloc((size_t)1024 * 1024 * 2);
  unsigned short* WoT   = (unsigned short*)alloc((size_t)1024 * 1024 * 2);
  unsigned short* drive = (unsigned short*)alloc((size_t)16777216 * 2);
  unsigned short* hs    = (unsigned short*)alloc((size_t)16777216 * 2);
  unsigned int*   hq    = (unsigned int*)alloc((size_t)8 * 2 * 1024 * 4);  // 64KB

  // conversions / init
  k_cvt_bf16<<<16384, 256, 0, stream>>>(x, xb, 4194304);
  k_transpose_bf16<<<dim3(96, 32), 256, 0, stream>>>(W_in, WinT, 1024, 3072);
  k_transpose_bf16<<<dim3(64, 32), 256, 0, stream>>>(W_gate, WgT, 1024, 2048);
  k_transpose_bf16<<<dim3(32, 32), 256, 0, stream>>>(W_rec, WrT, 1024, 1024);
  k_transpose_bf16<<<dim3(32, 32), 256, 0, stream>>>(W_out, WoT, 1024, 1024);
  k_init_hq<<<32, 256, 0, stream>>>(h0, hq);

  // drive = silu(u)*silu(v)+w
  k_gemm_drive<<<dim3(128, 16), 256, 0, stream>>>(xb, WinT, b_in, drive);
  // sequential recurrence: 8 batch rings x 32 WGs, self-served polls,
  // one barrier per step, 13-wave WGs
  k_scan<<<256, 832, 0, stream>>>(WgT, WrT, b_gate, b_rec, drive, hq,
                                  hs, outp + 16777216);
  // out = hs @ W_out + b_out
  k_gemm_out<<<dim3(128, 8), 256, 0, stream>>>(hs, WoT, b_out, outp);
}

// Round 17
// 4033.363 us; speedup vs baseline: 1.6396x; 1.0931x over previous
//
#include <hip/hip_runtime.h>

// ---------- types / helpers ----------
typedef short short8 __attribute__((ext_vector_type(8)));
typedef __bf16 bf16x8 __attribute__((ext_vector_type(8)));
typedef float f32x4 __attribute__((ext_vector_type(4)));
typedef float f32x4v __attribute__((ext_vector_type(4)));
typedef unsigned short u16x4 __attribute__((ext_vector_type(4)));
typedef unsigned int uint2v __attribute__((ext_vector_type(2)));
typedef unsigned long long u64;

__device__ __forceinline__ unsigned short f2b(float f) {
  unsigned x = __builtin_bit_cast(unsigned, f);
  x = x + 0x7fffu + ((x >> 16) & 1u);   // RNE (finite inputs)
  return (unsigned short)(x >> 16);
}
__device__ __forceinline__ float b2f(unsigned short u) {
  unsigned x = ((unsigned)u) << 16;
  return __builtin_bit_cast(float, x);
}
__device__ __forceinline__ f32x4 mfma16(short8 a, short8 b, f32x4 c) {
  return __builtin_amdgcn_mfma_f32_16x16x32_bf16(
      __builtin_bit_cast(bf16x8, a), __builtin_bit_cast(bf16x8, b), c, 0, 0, 0);
}
typedef const __attribute__((address_space(1))) void* gas_p;
typedef __attribute__((address_space(3))) void* las_p;
__device__ __forceinline__ void gload_lds16(const void* g, void* l) {
  __builtin_amdgcn_global_load_lds((gas_p)g, (las_p)l, 16, 0, 0);
}

// ---------- conversion kernels ----------
__global__ __launch_bounds__(256) void k_cvt_bf16(const float* __restrict__ in,
                                                  unsigned short* __restrict__ out,
                                                  int n4) {
  int i = blockIdx.x * 256 + threadIdx.x;
  if (i >= n4) return;
  f32x4v v = *(const f32x4v*)(in + (size_t)i * 4);
  u16x4 o;
  o[0] = f2b(v[0]); o[1] = f2b(v[1]); o[2] = f2b(v[2]); o[3] = f2b(v[3]);
  *(u16x4*)(out + (size_t)i * 4) = o;
}

// hq[b][0][i] = tag0 | bf16(h0[b][i]); hq[b][1][i] = 0  (tag 0 != any odd t)
__global__ __launch_bounds__(256) void k_init_hq(const float* __restrict__ h0,
                                                 unsigned int* __restrict__ hq) {
  int idx = blockIdx.x * 256 + threadIdx.x;
  if (idx >= 8192) return;
  int b = idx >> 10, i = idx & 1023;
  hq[(size_t)b * 2048 + i] = (unsigned int)f2b(h0[idx]);
  hq[(size_t)b * 2048 + 1024 + i] = 0u;
}

// out[c][r] = bf16(in[r][c]);  R,C multiples of 32
__global__ __launch_bounds__(256) void k_transpose_bf16(const float* __restrict__ in,
                                                        unsigned short* __restrict__ out,
                                                        int R, int C) {
  __shared__ unsigned short tile[32][33];
  int c0 = blockIdx.x * 32, r0 = blockIdx.y * 32;
  int tx = threadIdx.x & 31, ty = threadIdx.x >> 5;
#pragma unroll
  for (int i = 0; i < 4; i++) {
    int r = ty + i * 8;
    tile[r][tx] = f2b(in[(size_t)(r0 + r) * C + c0 + tx]);
  }
  __syncthreads();
#pragma unroll
  for (int i = 0; i < 4; i++) {
    int rr = ty + i * 8;
    out[(size_t)(c0 + rr) * R + r0 + tx] = tile[tx][rr];
  }
}

// ---------- GEMM1: drive = silu(u)*silu(v)+w ----------
__global__ __launch_bounds__(256) void k_gemm_drive(const unsigned short* __restrict__ xb,
                                                    const unsigned short* __restrict__ WinT,
                                                    const float* __restrict__ b_in,
                                                    unsigned short* __restrict__ drive) {
  __shared__ unsigned short At[128 * 32];
  __shared__ unsigned short Bt[3][64 * 32];
  const int tid = threadIdx.x;
  const int w = tid >> 6, l = tid & 63;
  const int wm = w >> 1, wn = w & 1;
  const int lr = l & 15, lk = (l >> 4) * 8;
  const int m0 = blockIdx.x * 128;
  const int j0 = blockIdx.y * 64;
  f32x4 acc[3][4][2];
#pragma unroll
  for (int s = 0; s < 3; s++)
#pragma unroll
    for (int mi = 0; mi < 4; mi++)
#pragma unroll
      for (int ni = 0; ni < 2; ni++)
#pragma unroll
        for (int e = 0; e < 4; e++) acc[s][mi][ni][e] = 0.f;

  const int sr = tid >> 2;
  const int skb = (tid & 3) * 8;
  for (int kt = 0; kt < 32; kt++) {
    const int k0 = kt * 32;
    gload_lds16(xb + (size_t)(m0 + sr) * 1024 + k0 + skb, &At[w * 512]);
    gload_lds16(xb + (size_t)(m0 + 64 + sr) * 1024 + k0 + skb, &At[2048 + w * 512]);
#pragma unroll
    for (int s = 0; s < 3; s++)
      gload_lds16(WinT + (size_t)(s * 1024 + j0 + sr) * 1024 + k0 + skb, &Bt[s][w * 512]);
    __syncthreads();
    short8 Af[4], Bf[3][2];
#pragma unroll
    for (int mi = 0; mi < 4; mi++)
      Af[mi] = *(const short8*)&At[(wm * 64 + mi * 16 + lr) * 32 + lk];
#pragma unroll
    for (int s = 0; s < 3; s++)
#pragma unroll
      for (int ni = 0; ni < 2; ni++)
        Bf[s][ni] = *(const short8*)&Bt[s][(wn * 32 + ni * 16 + lr) * 32 + lk];
#pragma unroll
    for (int s = 0; s < 3; s++)
#pragma unroll
      for (int mi = 0; mi < 4; mi++)
#pragma unroll
        for (int ni = 0; ni < 2; ni++)
          acc[s][mi][ni] = mfma16(Af[mi], Bf[s][ni], acc[s][mi][ni]);
    __syncthreads();
  }
#pragma unroll
  for (int ni = 0; ni < 2; ni++) {
    const int c = j0 + wn * 32 + ni * 16 + lr;
    const float bu = b_in[c], bv = b_in[1024 + c], bw = b_in[2048 + c];
#pragma unroll
    for (int mi = 0; mi < 4; mi++) {
      const int r0 = m0 + wm * 64 + mi * 16 + (l >> 4) * 4;
#pragma unroll
      for (int e = 0; e < 4; e++) {
        float u = acc[0][mi][ni][e] + bu;
        float v = acc[1][mi][ni][e] + bv;
        float wv = acc[2][mi][ni][e] + bw;
        float su = u / (1.f + __expf(-u));
        float sv = v / (1.f + __expf(-v));
        drive[(size_t)(r0 + e) * 1024 + c] = f2b(su * sv + wv);
      }
    }
  }
}

// ---------- persistent scan v17: minimal 4-wave self-serve WG ----------
// 256 WGs x 256 thr (4 waves, 1/CU). Ring=batch b=g>>5, slot s=g&31 owns
// features [32s,32s+32). Exchange protocol byte-identical to R10
// (hq[b][t&1][1024] tagged (t<<16)|bf16, sc1 relaxed agent atomics).
// Wave w = K-quarter kq: holds B-frags for ALL 3 mats x 2 col-tiles x its
// quarter (48 x short8 ~ 192 VGPR; 1 wave/SIMD so 512-VGPR budget), polls
// its own 256-feature h-slice (2 u64/lane, exact coverage - no redundancy),
// packs to a wave-private LDS strip, MFMAs immediately (intra-wave dep only).
// ONE barrier/step; wave 0 lanes<32 then reduce+gate+publish while waves 1-3
// already poll t+1. Hazards: buf double-buffered (verified), strips private,
// hq overwrite gated by R10's chained back-pressure argument.
__global__ __launch_bounds__(256, 1) void k_scan(const unsigned short* __restrict__ WgT,
                                                 const unsigned short* __restrict__ WrT,
                                                 const float* __restrict__ b_gate,
                                                 const float* __restrict__ b_rec,
                                                 const unsigned short* __restrict__ drive,
                                                 unsigned int* __restrict__ hq,
                                                 unsigned short* __restrict__ hs,
                                                 float* __restrict__ final_h) {
  const int g = blockIdx.x;           // 0..255
  const int b = g >> 5;               // batch / ring id
  const int s = g & 31;               // slot in ring
  const int tid = threadIdx.x;        // 0..255
  const int w = tid >> 6, l = tid & 63;   // w = kq

  __shared__ unsigned int strip[4][128];  // per-wave packed h-quarter (512B)
  __shared__ float buf[2][4][3][32];      // double-buffered row-0 partials

  // ---- B-frags: all 3 mats x 2 col-tiles x own K-quarter -> registers ----
  const int lr = l & 15, ko = l >> 4;
  const bool av = (lr == 0);              // A row-0 carrier lanes
  short8 Breg[3][2][8];
#pragma unroll
  for (int mat = 0; mat < 3; ++mat) {
    const unsigned short* WT = (mat == 2) ? WrT : WgT;
    const int rowbase = ((mat == 1) ? 1024 : 0) + s * 32;
#pragma unroll
    for (int t2 = 0; t2 < 2; ++t2)
#pragma unroll
      for (int ks = 0; ks < 8; ++ks)
        Breg[mat][t2][ks] =
            *(const short8*)&WT[(size_t)(rowbase + t2 * 16 + lr) * 1024 +
                                w * 256 + ks * 32 + ko * 8];
  }

  // ---- finisher setup (wave 0, lanes 0-31) ----
  const bool isfin = (w == 0) && (l < 32);
  const int fcol = s * 32 + l;            // valid when isfin
  float bgv = 0.f, bgt = 0.f, brc = 0.f;
  unsigned short dpf = 0;
  if (isfin) {
    bgv = b_gate[fcol]; bgt = b_gate[1024 + fcol]; brc = b_rec[fcol];
    dpf = drive[(size_t)(b * 2048 + 0) * 1024 + fcol];
  }

  for (int t = 0; t < 2048; ++t) {
    const int p = t & 1;

    // ---- poll OWN K-quarter of h_t (tags == t), 2 u64 per lane ----
    {
      const unsigned tg = (unsigned)t;
      const u64* hb = (const u64*)(hq + (size_t)(b * 2 + p) * 1024) + w * 128 + 2 * l;
      u64 v0 = 0, v1 = 0;
      unsigned pend = 3u;
      do {
        if (pend & 1u)
          v0 = __hip_atomic_load(hb, __ATOMIC_RELAXED, __HIP_MEMORY_SCOPE_AGENT);
        if (pend & 2u)
          v1 = __hip_atomic_load(hb + 1, __ATOMIC_RELAXED, __HIP_MEMORY_SCOPE_AGENT);
        unsigned np = 0;
        if ((((unsigned)v0 >> 16) != tg) | (((unsigned)(v0 >> 32) >> 16) != tg))
          np |= 1u;
        if ((((unsigned)v1 >> 16) != tg) | (((unsigned)(v1 >> 32) >> 16) != tg))
          np |= 2u;
        pend = np;
      } while (pend);
      uint2v pk;
      pk[0] = __builtin_amdgcn_perm((unsigned)(v0 >> 32), (unsigned)v0, 0x05040100u);
      pk[1] = __builtin_amdgcn_perm((unsigned)(v1 >> 32), (unsigned)v1, 0x05040100u);
      *(uint2v*)&strip[w][2 * l] = pk;    // wave-private strip
    }

    // ---- MFMA: 8 k-slices x 3 mats x 2 col-tiles (intra-wave LDS dep) ----
    {
      f32x4 acc[3][2];
#pragma unroll
      for (int mat = 0; mat < 3; ++mat)
#pragma unroll
        for (int t2 = 0; t2 < 2; ++t2)
#pragma unroll
          for (int e = 0; e < 4; ++e) acc[mat][t2][e] = 0.f;
      const char* base = (const char*)&strip[w][0] + ko * 16;
#pragma unroll
      for (int ks = 0; ks < 8; ++ks) {
        short8 Af;
#pragma unroll
        for (int e = 0; e < 8; ++e) Af[e] = 0;
        if (av) Af = *(const short8*)(base + ks * 64);
#pragma unroll
        for (int mat = 0; mat < 3; ++mat) {
          acc[mat][0] = mfma16(Af, Breg[mat][0][ks], acc[mat][0]);
          acc[mat][1] = mfma16(Af, Breg[mat][1][ks], acc[mat][1]);
        }
      }
      if (l < 16) {   // D row 0 lives in lanes 0-15, reg 0
#pragma unroll
        for (int mat = 0; mat < 3; ++mat) {
          buf[p][w][mat][l] = acc[mat][0][0];
          buf[p][w][mat][16 + l] = acc[mat][1][0];
        }
      }
    }
    __syncthreads();   // the only barrier: buf[p] complete

    // ---- finisher (wave 0): K-quarter reduce + gate + tagged publish ----
    // Waves 1-3 are already polling t+1 (strips private, buf double-buffered).
    if (isfin) {
      const float gv = ((buf[p][0][0][l] + buf[p][1][0][l]) +
                        (buf[p][2][0][l] + buf[p][3][0][l])) + bgv;
      const float gt = ((buf[p][0][1][l] + buf[p][1][1][l]) +
                        (buf[p][2][1][l] + buf[p][3][1][l])) + bgt;
      const float rc = ((buf[p][0][2][l] + buf[p][1][2][l]) +
                        (buf[p][2][2][l] + buf[p][3][2][l])) + brc;
      const float sgv = 1.f / (1.f + __expf(-gv));
      const float sgt = 1.f / (1.f + __expf(-gt));
      const float gate = sgv * gt * sgt;  // sigmoid(gv) * silu(gt)
      const float nh = gate * rc + (1.f - gate) * b2f(dpf);
      const unsigned short nhb = f2b(nh);
      __hip_atomic_store(hq + (size_t)(b * 2 + (p ^ 1)) * 1024 + fcol,
                         (((unsigned)(t + 1)) << 16) | (unsigned)nhb,
                         __ATOMIC_RELAXED, __HIP_MEMORY_SCOPE_AGENT);
      hs[(size_t)(b * 2048 + t) * 1024 + fcol] = nhb;
      if (t == 2047) final_h[b * 1024 + fcol] = nh;
      else dpf = drive[(size_t)(b * 2048 + t + 1) * 1024 + fcol];  // prefetch
    }
  }
}

// ---------- GEMM3: out = hs @ W_out + b_out ----------
__global__ __launch_bounds__(256) void k_gemm_out(const unsigned short* __restrict__ hs,
                                                  const unsigned short* __restrict__ WoT,
                                                  const float* __restrict__ b_out,
                                                  float* __restrict__ out) {
  __shared__ unsigned short At[128 * 32];
  __shared__ unsigned short Bt[128 * 32];
  const int tid = threadIdx.x;
  const int w = tid >> 6, l = tid & 63;
  const int wm = w >> 1, wn = w & 1;
  const int lr = l & 15, lk = (l >> 4) * 8;
  const int m0 = blockIdx.x * 128;
  const int n0 = blockIdx.y * 128;
  f32x4 acc[4][4];
#pragma unroll
  for (int mi = 0; mi < 4; mi++)
#pragma unroll
    for (int ni = 0; ni < 4; ni++)
#pragma unroll
      for (int e = 0; e < 4; e++) acc[mi][ni][e] = 0.f;

  const int sr = tid >> 2;
  const int skb = (tid & 3) * 8;
  for (int kt = 0; kt < 32; kt++) {
    const int k0 = kt * 32;
    gload_lds16(hs + (size_t)(m0 + sr) * 1024 + k0 + skb, &At[w * 512]);
    gload_lds16(hs + (size_t)(m0 + 64 + sr) * 1024 + k0 + skb, &At[2048 + w * 512]);
    gload_lds16(WoT + (size_t)(n0 + sr) * 1024 + k0 + skb, &Bt[w * 512]);
    gload_lds16(WoT + (size_t)(n0 + 64 + sr) * 1024 + k0 + skb, &Bt[2048 + w * 512]);
    __syncthreads();
    short8 Af[4], Bf[4];
#pragma unroll
    for (int mi = 0; mi < 4; mi++)
      Af[mi] = *(const short8*)&At[(wm * 64 + mi * 16 + lr) * 32 + lk];
#pragma unroll
    for (int ni = 0; ni < 4; ni++)
      Bf[ni] = *(const short8*)&Bt[(wn * 64 + ni * 16 + lr) * 32 + lk];
#pragma unroll
    for (int mi = 0; mi < 4; mi++)
#pragma unroll
      for (int ni = 0; ni < 4; ni++)
        acc[mi][ni] = mfma16(Af[mi], Bf[ni], acc[mi][ni]);
    __syncthreads();
  }
#pragma unroll
  for (int ni = 0; ni < 4; ni++) {
    const int c = n0 + wn * 64 + ni * 16 + lr;
    const float bo = b_out[c];
#pragma unroll
    for (int mi = 0; mi < 4; mi++) {
      const int r0 = m0 + wm * 64 + mi * 16 + (l >> 4) * 4;
#pragma unroll
      for (int e = 0; e < 4; e++)
        out[(size_t)(r0 + e) * 1024 + c] = acc[mi][ni][e] + bo;
    }
  }
}

// ---------- launch ----------
extern "C" void kernel_launch(void* const* d_in, const int* in_sizes, int n_in,
                              void* d_out, int out_size, void* d_ws, size_t ws_size,
                              hipStream_t stream) {
  const float* x      = (const float*)d_in[0];
  const float* h0     = (const float*)d_in[1];
  const float* W_in   = (const float*)d_in[2];
  const float* b_in   = (const float*)d_in[3];
  const float* W_gate = (const float*)d_in[4];
  const float* b_gate = (const float*)d_in[5];
  const float* W_rec  = (const float*)d_in[6];
  const float* b_rec  = (const float*)d_in[7];
  const float* W_out  = (const float*)d_in[8];
  const float* b_out  = (const float*)d_in[9];
  float* outp = (float*)d_out;

  size_t off = 0;
  auto alloc = [&](size_t bytes) {
    void* p = (char*)d_ws + off;
    off += (bytes + 255) & ~(size_t)255;
    return p;
  };
  unsigned short* xb    = (unsigned short*)alloc((size_t)16777216 * 2);
  unsigned short* WinT  = (unsigned short*)alloc((size_t)3072 * 1024 * 2);
  unsigned short* WgT   = (unsigned short*)alloc((size_t)2048 * 1024 * 2);
  unsigned short* WrT   = (unsigned short*)alloc((size_t)1024 * 1024 * 2);
  unsigned short* WoT   = (unsigned short*)alloc((size_t)1024 * 1024 * 2);
  unsigned short* drive = (unsigned short*)alloc((size_t)16777216 * 2);
  unsigned short* hs    = (unsigned short*)alloc((size_t)16777216 * 2);
  unsigned int*   hq    = (unsigned int*)alloc((size_t)8 * 2 * 1024 * 4);  // 64KB

  // conversions / init
  k_cvt_bf16<<<16384, 256, 0, stream>>>(x, xb, 4194304);
  k_transpose_bf16<<<dim3(96, 32), 256, 0, stream>>>(W_in, WinT, 1024, 3072);
  k_transpose_bf16<<<dim3(64, 32), 256, 0, stream>>>(W_gate, WgT, 1024, 2048);
  k_transpose_bf16<<<dim3(32, 32), 256, 0, stream>>>(W_rec, WrT, 1024, 1024);
  k_transpose_bf16<<<dim3(32, 32), 256, 0, stream>>>(W_out, WoT, 1024, 1024);
  k_init_hq<<<32, 256, 0, stream>>>(h0, hq);

  // drive = silu(u)*silu(v)+w
  k_gemm_drive<<<dim3(128, 16), 256, 0, stream>>>(xb, WinT, b_in, drive);
  // sequential recurrence: 8 batch rings x 32 WGs, minimal 4-wave WGs
  k_scan<<<256, 256, 0, stream>>>(WgT, WrT, b_gate, b_rec, drive, hq,
                                  hs, outp + 16777216);
  // out = hs @ W_out + b_out
  k_gemm_out<<<dim3(128, 8), 256, 0, stream>>>(hs, WoT, b_out, outp);
}